// Round 7
// baseline (6017.991 us; speedup 1.0000x reference)
//
#include <hip/hip_runtime.h>
#include <cstdint>
#include <cstddef>

#define HID   32
#define TLEN  4096
#define DIN   8
#define DOUT  80

typedef float v2f __attribute__((ext_vector_type(2)));
typedef float v4f __attribute__((ext_vector_type(4)));
typedef unsigned uv2 __attribute__((ext_vector_type(2)));

// sigmoid(x) = 1/(1+2^(-x*log2e)); saturates correctly at +-inf
__device__ __forceinline__ float fsig(float x) {
    float e = __builtin_amdgcn_exp2f(-1.442695041f * x);
    return __builtin_amdgcn_rcpf(1.0f + e);
}
__device__ __forceinline__ float bfbits(unsigned v) {
    union { unsigned u; float f; } c; c.u = v << 16; return c.f;
}
// dtype-agnostic scalar element load
__device__ __forceinline__ float ldf(const void* p, int idx, int isbf) {
    if (isbf) return bfbits(((const unsigned short*)p)[idx]);
    return ((const float*)p)[idx];
}
// Runtime dtype sniff (verified rounds 2-4).
__device__ __forceinline__ int tensor_is_bf16(const void* p, int elems, int lane) {
    int nw = elems >> 1; if (nw > 64) nw = 64;
    int e = 0;
    if (lane < nw) {
        unsigned w = ((const unsigned*)p)[lane];
        e = (int)((w >> 7) & 0xFF);
    }
    return __ballot(e >= 135) == 0ULL;
}

__device__ __forceinline__ int rdlane_i(int v, int l) {
#if __has_builtin(__builtin_amdgcn_readlane)
    return __builtin_amdgcn_readlane(v, l);
#else
    return __shfl(v, l);
#endif
}
__device__ __forceinline__ float rdlane(float v, int l) {
    return __int_as_float(rdlane_i(__float_as_int(v), l));
}
// SGPR-pair splat of lane l's float: both 32-bit halves = value.
// readlane -> SGPR; shift/or on SALU (parallel pipe, ~free).
__device__ __forceinline__ unsigned long long splat2(float v, int l) {
    unsigned u = (unsigned)rdlane_i(__float_as_int(v), l);
    return ((unsigned long long)u << 32) | (unsigned long long)u;
}

// pull_upper: lanes 0..31 receive the value held by lane+32 (verified correct
// rounds 2-4 via runtime psel probe + passing harness).
__device__ __forceinline__ float pull_upper(float v, int sel) {
#if __has_builtin(__builtin_amdgcn_permlane32_swap)
    uv2 r = __builtin_amdgcn_permlane32_swap(__float_as_uint(v), __float_as_uint(v),
                                             false, false);
    return __uint_as_float(sel ? r.x : r.y);
#else
    (void)sel;
    return __shfl_xor(v, 32);
#endif
}
__device__ __forceinline__ int probe_swap_sel(int lane) {
#if __has_builtin(__builtin_amdgcn_permlane32_swap)
    uv2 r = __builtin_amdgcn_permlane32_swap((unsigned)lane, (unsigned)lane,
                                             false, false);
    return (rdlane_i((int)r.x, 0) == 32) ? 1 : 0;
#else
    return 0;
#endif
}

// Packed fp32 FMA: acc(2) += w(2) * {h,h}. One instruction for 2 FLOPs;
// h splat comes in as an SGPR pair (1 scalar read allowed per VALU op).
#define PKFMA(acc, w, hh) \
    asm("v_pk_fma_f32 %0, %1, %2, %0" : "+v"(acc) : "v"(w), "s"(hh))

// LDS weight planes, EXACTLY 64 KiB total (2 planes x 64 rows x 128 floats).
// plane[l][k] is a float4 holding two matrices' rows l and l+64 at column k.
// Conflict avoidance via XOR column swizzle instead of row padding:
//   word offset = plane*8192 + l*128 + ((4k) ^ (4*(l&7)))
// Group-start bank = 4*((k%8) ^ (l&7)): for fixed k the 64 lanes spread
// uniformly over all 8 bank-groups -> 8 words/bank per wave64 ds_read_b128
// (the LDS minimum). Each lane reads only rows it wrote -> no barrier needed.
#define PLANE_WORDS (64 * 128)

// One wave per batch element. Lane j owns gate rows j and j+64 of each 128-row
// gate matrix: lane j<32 holds (i_j, g_j), lane j+32 holds (f_j, o_j).
// Weights live in LDS (not registers): rounds 2-4 proved the allocator spills
// per-lane register staging to scratch; AGPR staging costs an AREAD per fma.
// ds_read_b128 issues on the LDS pipe and overlaps the v_pk_fma_f32 stream.
// NO barriers (single wave). h broadcast via v_readlane -> SGPR-pair splat.
__global__ __launch_bounds__(64)
void lstm_seq_kernel(const void* __restrict__ gx,
                     const void* __restrict__ gWih1,
                     const void* __restrict__ gWhh1,
                     const void* __restrict__ gbih1,
                     const void* __restrict__ gbhh1,
                     const void* __restrict__ gWih2,
                     const void* __restrict__ gWhh2,
                     const void* __restrict__ gbih2,
                     const void* __restrict__ gbhh2,
                     const void* __restrict__ gWlin,
                     const void* __restrict__ gblin,
                     float* __restrict__ gout,
                     int xelems)
{
    const int lane = threadIdx.x;
    const int b    = blockIdx.x;

    __shared__ __align__(16) float sh[2 * PLANE_WORDS];   // 65536 B exactly

    const int psel = probe_swap_sel(lane);

    // ---- per-tensor dtype detection (wave-uniform, identical in all blocks) ----
    const int xbf  = tensor_is_bf16(gx,    xelems,    lane);
    const int w1bf = tensor_is_bf16(gWih1, 4*HID*DIN, lane);
    const int h1bf = tensor_is_bf16(gWhh1, 4*HID*HID, lane);
    const int a1bf = tensor_is_bf16(gbih1, 4*HID,     lane);
    const int c1bf = tensor_is_bf16(gbhh1, 4*HID,     lane);
    const int w2bf = tensor_is_bf16(gWih2, 4*HID*HID, lane);
    const int h2bf = tensor_is_bf16(gWhh2, 4*HID*HID, lane);
    const int a2bf = tensor_is_bf16(gbih2, 4*HID,     lane);
    const int c2bf = tensor_is_bf16(gbhh2, 4*HID,     lane);
    const int wlbf = tensor_is_bf16(gWlin, DOUT*HID,  lane);
    const int blbf = tensor_is_bf16(gblin, DOUT,      lane);

    const int r0 = lane;        // i (lane<32) / f (lane>=32)
    const int r1 = lane + 64;   // g (lane<32) / o (lane>=32)
    const int rlo = lane;                                  // Wlin rows 0..63
    const int rhi = (lane < DOUT - 64) ? lane + 64 : lane; // rows 64..79 on lanes 0..15

    // per-lane swizzled base/column helpers
    const int lbase = lane * 128;           // words
    const int x7    = 4 * (lane & 7);       // XOR pattern (words)

    // ---- stage weights into LDS planes (one-time; amortized over 4096 steps) ----
    // plane0[l][k] = {Wih2[l][k], Wih2[l+64][k], Whh1[l][k], Whh1[l+64][k]}
    // plane1[l][k] = {Whh2[l][k], Whh2[l+64][k], Wlin[rlo][k], Wlin[rhi][k]}
    {
#pragma unroll
        for (int k = 0; k < HID; ++k) {
            const int col = (4 * k) ^ x7;
            v4f v1 = { ldf(gWih2, r0 * HID + k, w2bf),
                       ldf(gWih2, r1 * HID + k, w2bf),
                       ldf(gWhh1, r0 * HID + k, h1bf),
                       ldf(gWhh1, r1 * HID + k, h1bf) };
            *(v4f*)&sh[lbase + col] = v1;
            v4f v2 = { ldf(gWhh2, r0 * HID + k, h2bf),
                       ldf(gWhh2, r1 * HID + k, h2bf),
                       ldf(gWlin, rlo * HID + k, wlbf),
                       ldf(gWlin, rhi * HID + k, wlbf) };
            *(v4f*)&sh[PLANE_WORDS + lbase + col] = v2;
        }
    }

    // ---- small stuff in VGPRs: Wih1 (16 regs) + biases ----
    float w1x[DIN], w1y[DIN];
#pragma unroll
    for (int k = 0; k < DIN; ++k) {
        w1x[k] = ldf(gWih1, r0 * DIN + k, w1bf);
        w1y[k] = ldf(gWih1, r1 * DIN + k, w1bf);
    }
    const float b1x = ldf(gbih1, r0, a1bf) + ldf(gbhh1, r0, c1bf);
    const float b1y = ldf(gbih1, r1, a1bf) + ldf(gbhh1, r1, c1bf);
    const v2f bias2 = { ldf(gbih2, r0, a2bf) + ldf(gbhh2, r0, c2bf),
                        ldf(gbih2, r1, a2bf) + ldf(gbhh2, r1, c2bf) };
    const v2f biasl = { ldf(gblin, lane, blbf),
                        (lane < 16) ? ldf(gblin, lane + 64, blbf) : 0.0f };

    // Per-lane activation constants for the second gate component:
    // low lanes (g gate) need tanh, high lanes (o gate) need sigmoid.
    const float eY = (lane < HID) ? -2.885390082f : -1.442695041f;
    const float mY = (lane < HID) ?  2.0f : 1.0f;
    const float aY = (lane < HID) ? -1.0f : 0.0f;

    // x: 8 values per step, wave-uniform address; width depends on dtype
    const char* xbase = (const char*)gx +
        (size_t)b * TLEN * DIN * (xbf ? 2 : 4);
    auto load_x = [&](float* d, int t) {
        if (xbf) {
            uint4 u = ((const uint4*)xbase)[t];          // 8 bf16 = 16B
            d[0] = bfbits(u.x & 0xffffu); d[1] = bfbits(u.x >> 16);
            d[2] = bfbits(u.y & 0xffffu); d[3] = bfbits(u.y >> 16);
            d[4] = bfbits(u.z & 0xffffu); d[5] = bfbits(u.z >> 16);
            d[6] = bfbits(u.w & 0xffffu); d[7] = bfbits(u.w >> 16);
        } else {
            float4 a = ((const float4*)xbase)[2*t];      // 8 fp32 = 32B
            float4 c = ((const float4*)xbase)[2*t + 1];
            d[0] = a.x; d[1] = a.y; d[2] = a.z; d[3] = a.w;
            d[4] = c.x; d[5] = c.y; d[6] = c.z; d[7] = c.w;
        }
    };
    // bias1 + Wih1 . x — independent of the recurrence
    auto xgate = [&](const float* xv) -> v2f {
        float axx = 0, ayy = 0, bxx = 0, byy = 0;
#pragma unroll
        for (int k = 0; k < DIN; k += 2) {
            axx = fmaf(w1x[k],   xv[k],   axx);
            ayy = fmaf(w1y[k],   xv[k],   ayy);
            bxx = fmaf(w1x[k+1], xv[k+1], bxx);
            byy = fmaf(w1y[k+1], xv[k+1], byy);
        }
        return (v2f){ b1x + (axx + bxx), b1y + (ayy + byy) };
    };

    float* outp = gout + (size_t)b * TLEN * DOUT;

    float c1 = 0.0f, c2 = 0.0f;      // valid on lanes<32; junk elsewhere (never read)
    v2f p1 = {0, 0};                 // Whh1 . h1_{t-1}
    v2f p2 = {0, 0};                 // Whh2 . h2_{t-1}

    float xn1[DIN], xn2[DIN];
    v2f g1b;
    {
        float x0[DIN];
        load_x(x0, 0);
        load_x(xn1, 1);
        load_x(xn2, 2);
        g1b = xgate(x0);
    }

#pragma unroll 1
    for (int t = 0; t < TLEN; ++t) {
        // Stop LICM from hoisting the (loop-invariant) LDS weight loads into
        // registers — that recreates the round-3 spill disaster. Registers are
        // unaffected; only memory values must be re-read each iteration.
        asm volatile("" ::: "memory");

        // far prefetch; consumed 2 iterations from now
        float xn3[DIN] = {0,0,0,0,0,0,0,0};
        if (t + 3 < TLEN) load_x(xn3, t + 3);

        // ---- layer-1 gates: pre1 (last iter's round 1) + bias + Wih1.x ----
        v2f g1 = p1 + g1b;

        float A1 = fsig(g1.x);
        float e1 = __builtin_amdgcn_exp2f(eY * g1.y);
        float B1 = fmaf(__builtin_amdgcn_rcpf(1.0f + e1), mY, aY);
        float sf1 = pull_upper(A1, psel);    // sig(f) -> low lanes
        float so1 = pull_upper(B1, psel);    // sig(o) -> low lanes
        c1 = fmaf(sf1, c1, A1 * B1);         // sig(f)*c + sig(i)*tanh(g)
        float ec1 = __builtin_amdgcn_exp2f(-2.885390082f * c1);
        float h1n = so1 * fmaf(__builtin_amdgcn_rcpf(1.0f + ec1), 2.0f, -1.0f);

        // independent filler work: next step's x-gates (uses x(t+1))
        v2f g1b_next = xgate(xn1);

        // ---- round 1: g2 (Wih2) AND next pre1 (Whh1), both from plane0 ----
        v2f q0 = {0,0}, q1 = {0,0};   // Wih2 . h1 partials
        v2f n0 = {0,0}, n1 = {0,0};   // Whh1 . h1 partials
#pragma unroll
        for (int k = 0; k < HID; k += 2) {
            v4f fa = *(const v4f*)&sh[lbase + ((4*k) ^ x7)];
            v4f fb = *(const v4f*)&sh[lbase + ((4*(k+1)) ^ x7)];
            unsigned long long ha = splat2(h1n, k);
            unsigned long long hb = splat2(h1n, k + 1);
            v2f wa0 = fa.xy, wa1 = fa.zw;
            v2f wb0 = fb.xy, wb1 = fb.zw;
            PKFMA(q0, wa0, ha);
            PKFMA(n0, wa1, ha);
            PKFMA(q1, wb0, hb);
            PKFMA(n1, wb1, hb);
        }
        p1 = n0 + n1;
        v2f g2 = (q0 + q1) + (p2 + bias2);

        // ---- layer-2 cell update ----
        float A2 = fsig(g2.x);
        float e2 = __builtin_amdgcn_exp2f(eY * g2.y);
        float B2 = fmaf(__builtin_amdgcn_rcpf(1.0f + e2), mY, aY);
        float sf2 = pull_upper(A2, psel);
        float so2 = pull_upper(B2, psel);
        c2 = fmaf(sf2, c2, A2 * B2);
        float ec2 = __builtin_amdgcn_exp2f(-2.885390082f * c2);
        float h2n = so2 * fmaf(__builtin_amdgcn_rcpf(1.0f + ec2), 2.0f, -1.0f);

        // ---- round 2: next pre2 (Whh2) AND output proj (Wlin), from plane1 ----
        v2f m0 = {0,0}, m1 = {0,0};   // Whh2 . h2 partials
        v2f o0 = biasl, o1 = {0,0};   // Wlin . h2 partials
#pragma unroll
        for (int k = 0; k < HID; k += 2) {
            v4f fa = *(const v4f*)&sh[PLANE_WORDS + lbase + ((4*k) ^ x7)];
            v4f fb = *(const v4f*)&sh[PLANE_WORDS + lbase + ((4*(k+1)) ^ x7)];
            unsigned long long ha = splat2(h2n, k);
            unsigned long long hb = splat2(h2n, k + 1);
            v2f wa0 = fa.xy, wa1 = fa.zw;
            v2f wb0 = fb.xy, wb1 = fb.zw;
            PKFMA(m0, wa0, ha);
            PKFMA(o0, wa1, ha);
            PKFMA(m1, wb0, hb);
            PKFMA(o1, wb1, hb);
        }
        p2 = m0 + m1;
        v2f oacc = o0 + o1;

        float* op = outp + (size_t)t * DOUT;
        op[lane] = oacc.x;                       // rows 0..63
        if (lane < 16) op[64 + lane] = oacc.y;   // rows 64..79

        // rotate x pipeline
        g1b = g1b_next;
#pragma unroll
        for (int k = 0; k < DIN; ++k) { xn1[k] = xn2[k]; xn2[k] = xn3[k]; }
    }
}

extern "C" void kernel_launch(void* const* d_in, const int* in_sizes, int n_in,
                              void* d_out, int out_size, void* d_ws, size_t ws_size,
                              hipStream_t stream)
{
    float* out = (float*)d_out;
    const int xelems = in_sizes[0];
    const int B = xelems / (TLEN * DIN);   // 256 (element count, dtype-independent)
    lstm_seq_kernel<<<B, 64, 0, stream>>>(d_in[0], d_in[1], d_in[2], d_in[3],
                                          d_in[4], d_in[5], d_in[6], d_in[7],
                                          d_in[8], d_in[9], d_in[10],
                                          out, xelems);
}